// Round 2
// baseline (7091.103 us; speedup 1.0000x reference)
//
#include <hip/hip_runtime.h>
#include <math.h>

// Problem constants
#define BB   32
#define CIN  16
#define C1   72      // (16+2)*2*2
#define NTOK 1024    // 32*32
#define HH   64
#define WW2  64

// ---------------------------------------------------------------------------
// Kernel 1: coord-concat + pixel_unshuffle -> t [B,72,1024]; per-token
// channel-norm -> tn. One thread per (b, token).
// ---------------------------------------------------------------------------
__global__ __launch_bounds__(256) void k1_build(const float* __restrict__ x,
                                                float* __restrict__ t,
                                                float* __restrict__ tn) {
  int gid = blockIdx.x * 256 + threadIdx.x;   // 32768 threads
  int b = gid >> 10;
  int n = gid & 1023;
  int hh = n >> 5, ww = n & 31;
  float vals[C1];
  float ss = 0.f;
#pragma unroll
  for (int c1 = 0; c1 < C1; ++c1) {
    int c = c1 >> 2, sh = (c1 >> 1) & 1, sw = c1 & 1;
    int h = 2 * hh + sh, w = 2 * ww + sw;
    float val;
    if (c < CIN) {
      val = x[((b * CIN + c) * HH + h) * WW2 + w];
    } else {
      float r = fmaxf(sqrtf((float)(h * h + w * w)), 1e-12f);
      val = (c == CIN ? (float)h : (float)w) / r;
    }
    vals[c1] = val;
    ss += val * val;
  }
  float inv = 1.0f / fmaxf(sqrtf(ss), 1e-12f);
#pragma unroll
  for (int c1 = 0; c1 < C1; ++c1) {
    int o = (b * C1 + c1) * NTOK + n;
    t[o]  = vals[c1];
    tn[o] = vals[c1] * inv;
  }
}

// ---------------------------------------------------------------------------
// Kernel 2: V = t @ Wv^T + bv.  A [2304][1024] (K contiguous), Wv [1024][1024]
// (K contiguous) -> NT GEMM. 64x64 tile, BK=16, 256 threads, 4x4 micro-tile.
// (unchanged this round — isolate the k3 fix)
// ---------------------------------------------------------------------------
#define K2_BK 16
__global__ __launch_bounds__(256) void k2_vproj(const float* __restrict__ A,
                                                const float* __restrict__ Wv,
                                                const float* __restrict__ bv,
                                                float* __restrict__ V) {
  __shared__ float As[64][K2_BK + 4];   // row stride 20 dwords
  __shared__ float Bs[64][K2_BK + 4];
  int tid = threadIdx.x;
  int row0 = blockIdx.x * 64;   // 36 blocks
  int col0 = blockIdx.y * 64;   // 16 blocks
  int tx = tid & 15, ty = tid >> 4;
  int lr = tid >> 2;            // 0..63
  int lk = (tid & 3) << 2;      // 0,4,8,12
  float acc[4][4];
#pragma unroll
  for (int i = 0; i < 4; ++i)
#pragma unroll
    for (int j = 0; j < 4; ++j) acc[i][j] = 0.f;

  for (int kt = 0; kt < 1024; kt += K2_BK) {
    float4 a4 = *(const float4*)&A[(row0 + lr) * 1024 + kt + lk];
    float4 b4 = *(const float4*)&Wv[(col0 + lr) * 1024 + kt + lk];
    *(float4*)&As[lr][lk] = a4;
    *(float4*)&Bs[lr][lk] = b4;
    __syncthreads();
#pragma unroll
    for (int kq = 0; kq < K2_BK; kq += 4) {
      float4 a[4], bbv[4];
#pragma unroll
      for (int i = 0; i < 4; ++i) a[i] = *(const float4*)&As[ty * 4 + i][kq];
#pragma unroll
      for (int j = 0; j < 4; ++j) bbv[j] = *(const float4*)&Bs[tx + 16 * j][kq];
#pragma unroll
      for (int i = 0; i < 4; ++i)
#pragma unroll
        for (int j = 0; j < 4; ++j)
          acc[i][j] += a[i].x * bbv[j].x + a[i].y * bbv[j].y +
                       a[i].z * bbv[j].z + a[i].w * bbv[j].w;
    }
    __syncthreads();
  }
#pragma unroll
  for (int i = 0; i < 4; ++i) {
    int r = row0 + ty * 4 + i;
#pragma unroll
    for (int j = 0; j < 4; ++j) {
      int cidx = col0 + tx + 16 * j;
      V[r * 1024 + cidx] = acc[i][j] + bv[cidx];
    }
  }
}

// ---------------------------------------------------------------------------
// Kernel 3 (REWRITTEN): cosine-sim rows + online top-3 + softmax.
// Round-0 version spilled the per-thread 72-float row fragment to scratch
// (2 GB writes, VALUBusy 5%). Now BOTH row fragments and m-tiles live in LDS:
//   arow[72][64]  — this block's 64 rows, staged once
//   btile[72][64] — current m-tile, staged per iteration
// Block = 256 threads = 64 rows (lane) x 4 m-splits (wave). Per-thread state:
// 4 named float4 accumulators + top-3 scalars (~45 VGPRs, no arrays).
// LDS reads: arow[c][lane] stride-1 (2-way = free), btile broadcast (free).
// ---------------------------------------------------------------------------
__global__ __launch_bounds__(256) void k3_topk(const float* __restrict__ tn,
                                               int* __restrict__ idxo,
                                               float* __restrict__ attno) {
  __shared__ float arow[C1][64];
  __shared__ float btile[C1][64];
  __shared__ float mv[256 * 3];
  __shared__ int   mi[256 * 3];
  int b  = blockIdx.y;
  int n0 = blockIdx.x * 64;
  int tid = threadIdx.x;
  int s = tid >> 6, r = tid & 63;     // s: wave = m-split, r: lane = row

  // stage this block's 64 row fragments (72 channels)
  for (int e4 = tid; e4 < C1 * 16; e4 += 256) {
    int c = e4 >> 4, q = e4 & 15;
    *(float4*)&arow[c][q * 4] =
        *(const float4*)&tn[(b * C1 + c) * NTOK + n0 + q * 4];
  }

  float v0 = -INFINITY, v1 = -INFINITY, v2 = -INFINITY;
  int   i0 = 0x7fffffff, i1 = 0x7fffffff, i2 = 0x7fffffff;
  auto ins = [&](float d, int di) {
    if (d > v0 || (d == v0 && di < i0)) {
      v2 = v1; i2 = i1; v1 = v0; i1 = i0; v0 = d; i0 = di;
    } else if (d > v1 || (d == v1 && di < i1)) {
      v2 = v1; i2 = i1; v1 = d; i1 = di;
    } else if (d > v2 || (d == v2 && di < i2)) {
      v2 = d; i2 = di;
    }
  };

#pragma unroll 1
  for (int tl = 0; tl < 16; ++tl) {
    int m0 = tl * 64;
    __syncthreads();   // previous tile consumed (also covers arow staging)
    for (int e4 = tid; e4 < C1 * 16; e4 += 256) {
      int c = e4 >> 4, q = e4 & 15;
      *(float4*)&btile[c][q * 4] =
          *(const float4*)&tn[(b * C1 + c) * NTOK + m0 + q * 4];
    }
    __syncthreads();

    float4 d0 = {0,0,0,0}, d1 = {0,0,0,0}, d2 = {0,0,0,0}, d3 = {0,0,0,0};
#pragma unroll
    for (int c = 0; c < C1; ++c) {
      float a = arow[c][r];
      float4 b0 = *(const float4*)&btile[c][s * 16 + 0];
      float4 b1 = *(const float4*)&btile[c][s * 16 + 4];
      float4 b2 = *(const float4*)&btile[c][s * 16 + 8];
      float4 b3 = *(const float4*)&btile[c][s * 16 + 12];
      d0.x += a * b0.x; d0.y += a * b0.y; d0.z += a * b0.z; d0.w += a * b0.w;
      d1.x += a * b1.x; d1.y += a * b1.y; d1.z += a * b1.z; d1.w += a * b1.w;
      d2.x += a * b2.x; d2.y += a * b2.y; d2.z += a * b2.z; d2.w += a * b2.w;
      d3.x += a * b3.x; d3.y += a * b3.y; d3.z += a * b3.z; d3.w += a * b3.w;
    }
    int mg = m0 + s * 16;
    ins(d0.x, mg + 0);  ins(d0.y, mg + 1);  ins(d0.z, mg + 2);  ins(d0.w, mg + 3);
    ins(d1.x, mg + 4);  ins(d1.y, mg + 5);  ins(d1.z, mg + 6);  ins(d1.w, mg + 7);
    ins(d2.x, mg + 8);  ins(d2.y, mg + 9);  ins(d2.z, mg + 10); ins(d2.w, mg + 11);
    ins(d3.x, mg + 12); ins(d3.y, mg + 13); ins(d3.z, mg + 14); ins(d3.w, mg + 15);
  }

  // 4-way merge across m-splits (comparator is a strict total order on
  // (val desc, idx asc), so merge order cannot affect the result)
  int base = (r * 4 + s) * 3;
  mv[base] = v0; mv[base + 1] = v1; mv[base + 2] = v2;
  mi[base] = i0; mi[base + 1] = i1; mi[base + 2] = i2;
  __syncthreads();
  if (tid < 64) {
    v0 = v1 = v2 = -INFINITY;
    i0 = i1 = i2 = 0x7fffffff;
#pragma unroll
    for (int s2 = 0; s2 < 4; ++s2) {
#pragma unroll
      for (int j = 0; j < 3; ++j) {
        int bi = (tid * 4 + s2) * 3 + j;
        ins(mv[bi], mi[bi]);
      }
    }
    float e1 = expf(v1 - v0), e2 = expf(v2 - v0);
    float inv = 1.0f / (1.0f + e1 + e2);
    int nn = n0 + tid;
    int ob = (b * NTOK + nn) * 3;
    idxo[ob] = i0; idxo[ob + 1] = i1; idxo[ob + 2] = i2;
    attno[ob] = inv; attno[ob + 1] = e1 * inv; attno[ob + 2] = e2 * inv;
  }
}

// ---------------------------------------------------------------------------
// Kernel 4: gather top-3 neighbor value columns (x attn) into LDS, then
// conv1d(kernel=K,stride=K) == [72 x 216] GEMM per token. (unchanged)
// ---------------------------------------------------------------------------
__global__ __launch_bounds__(256) void k4_conv1d(const float* __restrict__ v,
                                                 const int* __restrict__ idx,
                                                 const float* __restrict__ attn,
                                                 const float* __restrict__ conv_w,
                                                 const float* __restrict__ conv_b,
                                                 float* __restrict__ out1d) {
  __shared__ float prime[64][220];
  __shared__ int   sidx[64][3];
  __shared__ float satt[64][3];
  int b  = blockIdx.y;
  int n0 = blockIdx.x * 64;
  int tid = threadIdx.x;
  if (tid < 192) {
    int tok = tid / 3, k = tid % 3;
    sidx[tok][k] = idx[(b * NTOK + n0 + tok) * 3 + k];
    satt[tok][k] = attn[(b * NTOK + n0 + tok) * 3 + k];
  }
  __syncthreads();
  for (int e = tid; e < 64 * 216; e += 256) {
    int tok = e & 63, ck = e >> 6;
    int c = ck / 3, k = ck - c * 3;
    prime[tok][ck] = v[(b * C1 + c) * NTOK + sidx[tok][k]] * satt[tok][k];
  }
  __syncthreads();
  int tok = tid & 63;
  int obase = __builtin_amdgcn_readfirstlane((int)(tid >> 6)) * 18;
  float acc[18];
#pragma unroll
  for (int j = 0; j < 18; ++j) acc[j] = 0.f;
  for (int ck4 = 0; ck4 < 54; ++ck4) {
    float4 p4 = *(const float4*)&prime[tok][ck4 * 4];
#pragma unroll
    for (int j = 0; j < 18; ++j) {
      float4 w4 = *(const float4*)&conv_w[(obase + j) * 216 + ck4 * 4];
      acc[j] += p4.x * w4.x + p4.y * w4.y + p4.z * w4.z + p4.w * w4.w;
    }
  }
#pragma unroll
  for (int j = 0; j < 18; ++j) {
    int o = obase + j;
    out1d[(b * C1 + o) * NTOK + n0 + tok] = acc[j] + conv_b[o];
  }
}

// ---------------------------------------------------------------------------
// Kernel 5: pixel_shuffle + pointwise 1x1 conv. (unchanged)
// ---------------------------------------------------------------------------
__global__ __launch_bounds__(256) void k5_pw(const float* __restrict__ out1d,
                                             const float* __restrict__ pw_w,
                                             const float* __restrict__ pw_b,
                                             float* __restrict__ out) {
  int gid = blockIdx.x * 256 + threadIdx.x;   // 131072 threads
  int b = gid >> 12;
  int p = gid & 4095;
  int h = p >> 6, w = p & 63;
  int hh = h >> 1, ww = w >> 1;
  int c1base = ((h & 1) << 1) | (w & 1);
  int n = hh * 32 + ww;
  float xs[18];
#pragma unroll
  for (int c = 0; c < 18; ++c)
    xs[c] = out1d[(b * C1 + c * 4 + c1base) * NTOK + n];
#pragma unroll
  for (int o = 0; o < 16; ++o) {
    float a = pw_b[o];
#pragma unroll
    for (int c = 0; c < 18; ++c) a += xs[c] * pw_w[o * 18 + c];
    out[((b * 16 + o) << 12) + p] = a;
  }
}

// ---------------------------------------------------------------------------
extern "C" void kernel_launch(void* const* d_in, const int* in_sizes, int n_in,
                              void* d_out, int out_size, void* d_ws, size_t ws_size,
                              hipStream_t stream) {
  (void)in_sizes; (void)n_in; (void)out_size; (void)ws_size;
  const float* x      = (const float*)d_in[0];
  const float* Wv     = (const float*)d_in[1];
  const float* bv     = (const float*)d_in[2];
  const float* conv_w = (const float*)d_in[3];
  const float* conv_b = (const float*)d_in[4];
  const float* pw_w   = (const float*)d_in[5];
  const float* pw_b   = (const float*)d_in[6];
  float* out = (float*)d_out;

  const size_t SZ_T = (size_t)BB * C1 * NTOK * sizeof(float);   // 9,437,184
  char* ws = (char*)d_ws;
  float* t     = (float*)(ws);
  float* tn    = (float*)(ws + SZ_T);
  float* v     = (float*)(ws + 2 * SZ_T);
  int*   idx   = (int*)  (ws + 3 * SZ_T);
  float* attn  = (float*)(ws + 3 * SZ_T + 393216);
  float* out1d = (float*)(ws + 3 * SZ_T + 2 * 393216);

  k1_build<<<dim3((BB * NTOK) / 256), 256, 0, stream>>>(x, t, tn);
  k2_vproj<<<dim3(36, 16), 256, 0, stream>>>(t, Wv, bv, v);
  k3_topk <<<dim3(16, BB), 512 / 2, 0, stream>>>(tn, idx, attn);
  k4_conv1d<<<dim3(16, BB), 256, 0, stream>>>(v, idx, attn, conv_w, conv_b, out1d);
  k5_pw   <<<dim3((BB * 4096) / 256), 256, 0, stream>>>(out1d, pw_w, pw_b, out);
}

// Round 3
// 392.348 us; speedup vs baseline: 18.0735x; 18.0735x over previous
//
#include <hip/hip_runtime.h>
#include <math.h>

// Problem constants
#define BB   32
#define CIN  16
#define C1   72      // (16+2)*2*2
#define NTOK 1024    // 32*32
#define HH   64
#define WW2  64

// ---------------------------------------------------------------------------
// Kernel 1: coord-concat + pixel_unshuffle -> t [B,72,1024]; per-token
// channel-norm -> tn. One thread per (b, token). (unchanged)
// ---------------------------------------------------------------------------
__global__ __launch_bounds__(256) void k1_build(const float* __restrict__ x,
                                                float* __restrict__ t,
                                                float* __restrict__ tn) {
  int gid = blockIdx.x * 256 + threadIdx.x;   // 32768 threads
  int b = gid >> 10;
  int n = gid & 1023;
  int hh = n >> 5, ww = n & 31;
  float vals[C1];
  float ss = 0.f;
#pragma unroll
  for (int c1 = 0; c1 < C1; ++c1) {
    int c = c1 >> 2, sh = (c1 >> 1) & 1, sw = c1 & 1;
    int h = 2 * hh + sh, w = 2 * ww + sw;
    float val;
    if (c < CIN) {
      val = x[((b * CIN + c) * HH + h) * WW2 + w];
    } else {
      float r = fmaxf(sqrtf((float)(h * h + w * w)), 1e-12f);
      val = (c == CIN ? (float)h : (float)w) / r;
    }
    vals[c1] = val;
    ss += val * val;
  }
  float inv = 1.0f / fmaxf(sqrtf(ss), 1e-12f);
#pragma unroll
  for (int c1 = 0; c1 < C1; ++c1) {
    int o = (b * C1 + c1) * NTOK + n;
    t[o]  = vals[c1];
    tn[o] = vals[c1] * inv;
  }
}

// ---------------------------------------------------------------------------
// Kernel 2: V = t @ Wv^T + bv. 64x64 tile NT-GEMM. (unchanged)
// ---------------------------------------------------------------------------
#define K2_BK 16
__global__ __launch_bounds__(256) void k2_vproj(const float* __restrict__ A,
                                                const float* __restrict__ Wv,
                                                const float* __restrict__ bv,
                                                float* __restrict__ V) {
  __shared__ float As[64][K2_BK + 4];
  __shared__ float Bs[64][K2_BK + 4];
  int tid = threadIdx.x;
  int row0 = blockIdx.x * 64;
  int col0 = blockIdx.y * 64;
  int tx = tid & 15, ty = tid >> 4;
  int lr = tid >> 2;
  int lk = (tid & 3) << 2;
  float acc[4][4];
#pragma unroll
  for (int i = 0; i < 4; ++i)
#pragma unroll
    for (int j = 0; j < 4; ++j) acc[i][j] = 0.f;

  for (int kt = 0; kt < 1024; kt += K2_BK) {
    float4 a4 = *(const float4*)&A[(row0 + lr) * 1024 + kt + lk];
    float4 b4 = *(const float4*)&Wv[(col0 + lr) * 1024 + kt + lk];
    *(float4*)&As[lr][lk] = a4;
    *(float4*)&Bs[lr][lk] = b4;
    __syncthreads();
#pragma unroll
    for (int kq = 0; kq < K2_BK; kq += 4) {
      float4 a[4], bbv[4];
#pragma unroll
      for (int i = 0; i < 4; ++i) a[i] = *(const float4*)&As[ty * 4 + i][kq];
#pragma unroll
      for (int j = 0; j < 4; ++j) bbv[j] = *(const float4*)&Bs[tx + 16 * j][kq];
#pragma unroll
      for (int i = 0; i < 4; ++i)
#pragma unroll
        for (int j = 0; j < 4; ++j)
          acc[i][j] += a[i].x * bbv[j].x + a[i].y * bbv[j].y +
                       a[i].z * bbv[j].z + a[i].w * bbv[j].w;
    }
    __syncthreads();
  }
#pragma unroll
  for (int i = 0; i < 4; ++i) {
    int r = row0 + ty * 4 + i;
#pragma unroll
    for (int j = 0; j < 4; ++j) {
      int cidx = col0 + tx + 16 * j;
      V[r * 1024 + cidx] = acc[i][j] + bv[cidx];
    }
  }
}

// ---------------------------------------------------------------------------
// Kernel 3 (REWRITTEN v2): cosine-sim + online top-3 + softmax.
// Rounds 0/1 both died to register-spill scratch traffic (2-15 GB). This
// version is built so spilling is impossible:
//  - 4x4 register outer-product tile per thread: 2 LDS b128 reads feed 16
//    FMAs (av: 4-address broadcast conflict-free; bv: 16 addrs over 256B,
//    2-way = free per m136).
//  - c-loop `#pragma unroll 4` (NOT full 72-unroll -> bounded hoisting).
//  - __launch_bounds__(256, 4) caps VGPR at 128; state is ~70 VGPRs
//    (16 acc + 24 statically-indexed top-k scalars).
//  - top-3 merge reuses arow/btile LDS after a barrier (LDS stays 36 KB
//    -> 4 blocks/CU).
// Block = 256 threads = (16 row-groups x 4 rows) x (16 col-groups x 4 cols),
// iterating 16 col-tiles of 64.
// ---------------------------------------------------------------------------
#define INS(TV, TI, d, di)                                              \
  {                                                                     \
    if ((d) > TV[0] || ((d) == TV[0] && (di) < TI[0])) {                \
      TV[2] = TV[1]; TI[2] = TI[1];                                     \
      TV[1] = TV[0]; TI[1] = TI[0];                                     \
      TV[0] = (d);   TI[0] = (di);                                      \
    } else if ((d) > TV[1] || ((d) == TV[1] && (di) < TI[1])) {         \
      TV[2] = TV[1]; TI[2] = TI[1];                                     \
      TV[1] = (d);   TI[1] = (di);                                      \
    } else if ((d) > TV[2] || ((d) == TV[2] && (di) < TI[2])) {         \
      TV[2] = (d);   TI[2] = (di);                                      \
    }                                                                   \
  }

__global__ __launch_bounds__(256, 4) void k3_topk(const float* __restrict__ tn,
                                                  int* __restrict__ idxo,
                                                  float* __restrict__ attno) {
  __shared__ float arow[C1][64];    // [c][row in block]
  __shared__ float btile[C1][64];   // [c][col in tile]
  int b  = blockIdx.y;
  int n0 = blockIdx.x * 64;
  int tid = threadIdx.x;
  int tx = tid & 15;   // col group -> cols tx*4..tx*4+3
  int ty = tid >> 4;   // row group -> rows ty*4..ty*4+3

  // stage this block's 64 rows (72 channels), float4-coalesced
  for (int e4 = tid; e4 < C1 * 16; e4 += 256) {
    int c = e4 >> 4, q = e4 & 15;
    *(float4*)&arow[c][q * 4] =
        *(const float4*)&tn[(b * C1 + c) * NTOK + n0 + q * 4];
  }

  float tv[4][3];
  int   ti[4][3];
#pragma unroll
  for (int ri = 0; ri < 4; ++ri) {
    tv[ri][0] = tv[ri][1] = tv[ri][2] = -INFINITY;
    ti[ri][0] = ti[ri][1] = ti[ri][2] = 0x7fffffff;
  }

#pragma unroll 1
  for (int tl = 0; tl < 16; ++tl) {
    int m0 = tl * 64;
    __syncthreads();   // previous tile fully consumed (covers arow staging too)
    for (int e4 = tid; e4 < C1 * 16; e4 += 256) {
      int c = e4 >> 4, q = e4 & 15;
      *(float4*)&btile[c][q * 4] =
          *(const float4*)&tn[(b * C1 + c) * NTOK + m0 + q * 4];
    }
    __syncthreads();

    float4 acc0 = {0,0,0,0}, acc1 = {0,0,0,0}, acc2 = {0,0,0,0}, acc3 = {0,0,0,0};
#pragma unroll 4
    for (int c = 0; c < C1; ++c) {
      float4 av  = *(const float4*)&arow[c][ty * 4];
      float4 bv4 = *(const float4*)&btile[c][tx * 4];
      acc0.x += av.x * bv4.x; acc0.y += av.x * bv4.y;
      acc0.z += av.x * bv4.z; acc0.w += av.x * bv4.w;
      acc1.x += av.y * bv4.x; acc1.y += av.y * bv4.y;
      acc1.z += av.y * bv4.z; acc1.w += av.y * bv4.w;
      acc2.x += av.z * bv4.x; acc2.y += av.z * bv4.y;
      acc2.z += av.z * bv4.z; acc2.w += av.z * bv4.w;
      acc3.x += av.w * bv4.x; acc3.y += av.w * bv4.y;
      acc3.z += av.w * bv4.z; acc3.w += av.w * bv4.w;
    }
    int cb = m0 + tx * 4;
    INS(tv[0], ti[0], acc0.x, cb + 0); INS(tv[0], ti[0], acc0.y, cb + 1);
    INS(tv[0], ti[0], acc0.z, cb + 2); INS(tv[0], ti[0], acc0.w, cb + 3);
    INS(tv[1], ti[1], acc1.x, cb + 0); INS(tv[1], ti[1], acc1.y, cb + 1);
    INS(tv[1], ti[1], acc1.z, cb + 2); INS(tv[1], ti[1], acc1.w, cb + 3);
    INS(tv[2], ti[2], acc2.x, cb + 0); INS(tv[2], ti[2], acc2.y, cb + 1);
    INS(tv[2], ti[2], acc2.z, cb + 2); INS(tv[2], ti[2], acc2.w, cb + 3);
    INS(tv[3], ti[3], acc3.x, cb + 0); INS(tv[3], ti[3], acc3.y, cb + 1);
    INS(tv[3], ti[3], acc3.z, cb + 2); INS(tv[3], ti[3], acc3.w, cb + 3);
  }

  // merge 16 col-groups x 3 per row; reuse tile LDS as merge buffers
  __syncthreads();
  float* mv = &arow[0][0];          // needs 64*16*3 = 3072 floats (have 4608)
  int*   mi = (int*)&btile[0][0];
#pragma unroll
  for (int ri = 0; ri < 4; ++ri) {
    int row = ty * 4 + ri;
#pragma unroll
    for (int j = 0; j < 3; ++j) {
      mv[(row * 16 + tx) * 3 + j] = tv[ri][j];
      mi[(row * 16 + tx) * 3 + j] = ti[ri][j];
    }
  }
  __syncthreads();
  if (tid < 64) {
    float fv[3] = {-INFINITY, -INFINITY, -INFINITY};
    int   fi[3] = {0x7fffffff, 0x7fffffff, 0x7fffffff};
    for (int g = 0; g < 16; ++g) {
#pragma unroll
      for (int j = 0; j < 3; ++j) {
        float d  = mv[(tid * 16 + g) * 3 + j];
        int   di = mi[(tid * 16 + g) * 3 + j];
        INS(fv, fi, d, di);
      }
    }
    float e1 = expf(fv[1] - fv[0]), e2 = expf(fv[2] - fv[0]);
    float inv = 1.0f / (1.0f + e1 + e2);
    int ob = (b * NTOK + n0 + tid) * 3;
    idxo[ob] = fi[0]; idxo[ob + 1] = fi[1]; idxo[ob + 2] = fi[2];
    attno[ob] = inv; attno[ob + 1] = e1 * inv; attno[ob + 2] = e2 * inv;
  }
}

// ---------------------------------------------------------------------------
// Kernel 4: gather top-3 neighbor value columns (x attn) into LDS, then
// conv1d(kernel=K,stride=K) == [72 x 216] GEMM per token. (unchanged)
// ---------------------------------------------------------------------------
__global__ __launch_bounds__(256) void k4_conv1d(const float* __restrict__ v,
                                                 const int* __restrict__ idx,
                                                 const float* __restrict__ attn,
                                                 const float* __restrict__ conv_w,
                                                 const float* __restrict__ conv_b,
                                                 float* __restrict__ out1d) {
  __shared__ float prime[64][220];
  __shared__ int   sidx[64][3];
  __shared__ float satt[64][3];
  int b  = blockIdx.y;
  int n0 = blockIdx.x * 64;
  int tid = threadIdx.x;
  if (tid < 192) {
    int tok = tid / 3, k = tid % 3;
    sidx[tok][k] = idx[(b * NTOK + n0 + tok) * 3 + k];
    satt[tok][k] = attn[(b * NTOK + n0 + tok) * 3 + k];
  }
  __syncthreads();
  for (int e = tid; e < 64 * 216; e += 256) {
    int tok = e & 63, ck = e >> 6;
    int c = ck / 3, k = ck - c * 3;
    prime[tok][ck] = v[(b * C1 + c) * NTOK + sidx[tok][k]] * satt[tok][k];
  }
  __syncthreads();
  int tok = tid & 63;
  int obase = __builtin_amdgcn_readfirstlane((int)(tid >> 6)) * 18;
  float acc[18];
#pragma unroll
  for (int j = 0; j < 18; ++j) acc[j] = 0.f;
  for (int ck4 = 0; ck4 < 54; ++ck4) {
    float4 p4 = *(const float4*)&prime[tok][ck4 * 4];
#pragma unroll
    for (int j = 0; j < 18; ++j) {
      float4 w4 = *(const float4*)&conv_w[(obase + j) * 216 + ck4 * 4];
      acc[j] += p4.x * w4.x + p4.y * w4.y + p4.z * w4.z + p4.w * w4.w;
    }
  }
#pragma unroll
  for (int j = 0; j < 18; ++j) {
    int o = obase + j;
    out1d[(b * C1 + o) * NTOK + n0 + tok] = acc[j] + conv_b[o];
  }
}

// ---------------------------------------------------------------------------
// Kernel 5: pixel_shuffle + pointwise 1x1 conv. (unchanged)
// ---------------------------------------------------------------------------
__global__ __launch_bounds__(256) void k5_pw(const float* __restrict__ out1d,
                                             const float* __restrict__ pw_w,
                                             const float* __restrict__ pw_b,
                                             float* __restrict__ out) {
  int gid = blockIdx.x * 256 + threadIdx.x;   // 131072 threads
  int b = gid >> 12;
  int p = gid & 4095;
  int h = p >> 6, w = p & 63;
  int hh = h >> 1, ww = w >> 1;
  int c1base = ((h & 1) << 1) | (w & 1);
  int n = hh * 32 + ww;
  float xs[18];
#pragma unroll
  for (int c = 0; c < 18; ++c)
    xs[c] = out1d[(b * C1 + c * 4 + c1base) * NTOK + n];
#pragma unroll
  for (int o = 0; o < 16; ++o) {
    float a = pw_b[o];
#pragma unroll
    for (int c = 0; c < 18; ++c) a += xs[c] * pw_w[o * 18 + c];
    out[((b * 16 + o) << 12) + p] = a;
  }
}

// ---------------------------------------------------------------------------
extern "C" void kernel_launch(void* const* d_in, const int* in_sizes, int n_in,
                              void* d_out, int out_size, void* d_ws, size_t ws_size,
                              hipStream_t stream) {
  (void)in_sizes; (void)n_in; (void)out_size; (void)ws_size;
  const float* x      = (const float*)d_in[0];
  const float* Wv     = (const float*)d_in[1];
  const float* bv     = (const float*)d_in[2];
  const float* conv_w = (const float*)d_in[3];
  const float* conv_b = (const float*)d_in[4];
  const float* pw_w   = (const float*)d_in[5];
  const float* pw_b   = (const float*)d_in[6];
  float* out = (float*)d_out;

  const size_t SZ_T = (size_t)BB * C1 * NTOK * sizeof(float);   // 9,437,184
  char* ws = (char*)d_ws;
  float* t     = (float*)(ws);
  float* tn    = (float*)(ws + SZ_T);
  float* v     = (float*)(ws + 2 * SZ_T);
  int*   idx   = (int*)  (ws + 3 * SZ_T);
  float* attn  = (float*)(ws + 3 * SZ_T + 393216);
  float* out1d = (float*)(ws + 3 * SZ_T + 2 * 393216);

  k1_build<<<dim3((BB * NTOK) / 256), 256, 0, stream>>>(x, t, tn);
  k2_vproj<<<dim3(36, 16), 256, 0, stream>>>(t, Wv, bv, v);
  k3_topk <<<dim3(16, BB), 256, 0, stream>>>(tn, idx, attn);
  k4_conv1d<<<dim3(16, BB), 256, 0, stream>>>(v, idx, attn, conv_w, conv_b, out1d);
  k5_pw   <<<dim3((BB * 4096) / 256), 256, 0, stream>>>(out1d, pw_w, pw_b, out);
}

// Round 4
// 381.159 us; speedup vs baseline: 18.6040x; 1.0294x over previous
//
#include <hip/hip_runtime.h>
#include <math.h>

// Problem constants
#define BB   32
#define CIN  16
#define C1   72      // (16+2)*2*2
#define NTOK 1024    // 32*32
#define HH   64
#define WW2  64

// ---------------------------------------------------------------------------
// Kernel 1: coord-concat + pixel_unshuffle -> t [B,72,1024]; per-token
// channel-norm -> tn. One thread per (b, token). (unchanged)
// ---------------------------------------------------------------------------
__global__ __launch_bounds__(256) void k1_build(const float* __restrict__ x,
                                                float* __restrict__ t,
                                                float* __restrict__ tn) {
  int gid = blockIdx.x * 256 + threadIdx.x;   // 32768 threads
  int b = gid >> 10;
  int n = gid & 1023;
  int hh = n >> 5, ww = n & 31;
  float vals[C1];
  float ss = 0.f;
#pragma unroll
  for (int c1 = 0; c1 < C1; ++c1) {
    int c = c1 >> 2, sh = (c1 >> 1) & 1, sw = c1 & 1;
    int h = 2 * hh + sh, w = 2 * ww + sw;
    float val;
    if (c < CIN) {
      val = x[((b * CIN + c) * HH + h) * WW2 + w];
    } else {
      float r = fmaxf(sqrtf((float)(h * h + w * w)), 1e-12f);
      val = (c == CIN ? (float)h : (float)w) / r;
    }
    vals[c1] = val;
    ss += val * val;
  }
  float inv = 1.0f / fmaxf(sqrtf(ss), 1e-12f);
#pragma unroll
  for (int c1 = 0; c1 < C1; ++c1) {
    int o = (b * C1 + c1) * NTOK + n;
    t[o]  = vals[c1];
    tn[o] = vals[c1] * inv;
  }
}

// ---------------------------------------------------------------------------
// Kernel 2: V = t @ Wv^T + bv. 64x64 NT-GEMM tile, unchanged inner loop.
// NEW: 1D grid (576 = 8 XCD x 72) with XCD-aware bijective swizzle: each XCD
// owns 2 col-tiles (Wv working set 512 KB, L2-resident); consecutive q within
// an XCD share the same A row-tile (L2 reuse). Theory: k2 was ~200us from
// L2 thrash (per-XCD working set was the full 13.4 MB > 4 MB L2).
// ---------------------------------------------------------------------------
#define K2_BK 16
__global__ __launch_bounds__(256) void k2_vproj(const float* __restrict__ A,
                                                const float* __restrict__ Wv,
                                                const float* __restrict__ bv,
                                                float* __restrict__ V) {
  __shared__ float As[64][K2_BK + 4];
  __shared__ float Bs[64][K2_BK + 4];
  int wg = blockIdx.x;            // 0..575
  int xcd = wg & 7;
  int q = wg >> 3;                // 0..71
  int row0 = (q >> 1) * 64;       // 36 row tiles
  int col0 = (xcd * 2 + (q & 1)) * 64;  // 16 col tiles, 2 per XCD
  int tid = threadIdx.x;
  int tx = tid & 15, ty = tid >> 4;
  int lr = tid >> 2;
  int lk = (tid & 3) << 2;
  float acc[4][4];
#pragma unroll
  for (int i = 0; i < 4; ++i)
#pragma unroll
    for (int j = 0; j < 4; ++j) acc[i][j] = 0.f;

  for (int kt = 0; kt < 1024; kt += K2_BK) {
    float4 a4 = *(const float4*)&A[(row0 + lr) * 1024 + kt + lk];
    float4 b4 = *(const float4*)&Wv[(col0 + lr) * 1024 + kt + lk];
    *(float4*)&As[lr][lk] = a4;
    *(float4*)&Bs[lr][lk] = b4;
    __syncthreads();
#pragma unroll
    for (int kq = 0; kq < K2_BK; kq += 4) {
      float4 a[4], bbv[4];
#pragma unroll
      for (int i = 0; i < 4; ++i) a[i] = *(const float4*)&As[ty * 4 + i][kq];
#pragma unroll
      for (int j = 0; j < 4; ++j) bbv[j] = *(const float4*)&Bs[tx + 16 * j][kq];
#pragma unroll
      for (int i = 0; i < 4; ++i)
#pragma unroll
        for (int j = 0; j < 4; ++j)
          acc[i][j] += a[i].x * bbv[j].x + a[i].y * bbv[j].y +
                       a[i].z * bbv[j].z + a[i].w * bbv[j].w;
    }
    __syncthreads();
  }
#pragma unroll
  for (int i = 0; i < 4; ++i) {
    int r = row0 + ty * 4 + i;
#pragma unroll
    for (int j = 0; j < 4; ++j) {
      int cidx = col0 + tx + 16 * j;
      V[r * 1024 + cidx] = acc[i][j] + bv[cidx];
    }
  }
}

// ---------------------------------------------------------------------------
// Kernel 3 (v3): cosine-sim + online top-3 + softmax.
// v2 was correct (52 VGPR, no spill) but occupancy-limited (2 waves/SIMD).
// v3: 512-thread blocks, 64 rows x 128-col m-tiles (8 tiles), same 4x4
// per-thread economy -> 4 waves/SIMD (2 blocks/CU @ 55.3 KB LDS).
// Skip-max guard: a 4-col group can only touch top-3 if its max > tv[2]
// (exact: new indices always exceed stored ones, so ties never insert).
// XCD swizzle: 4 batches per XCD -> 1.15 MB L2 working set.
// ---------------------------------------------------------------------------
#define INS(TV, TI, d, di)                                              \
  {                                                                     \
    if ((d) > TV[0] || ((d) == TV[0] && (di) < TI[0])) {                \
      TV[2] = TV[1]; TI[2] = TI[1];                                     \
      TV[1] = TV[0]; TI[1] = TI[0];                                     \
      TV[0] = (d);   TI[0] = (di);                                      \
    } else if ((d) > TV[1] || ((d) == TV[1] && (di) < TI[1])) {         \
      TV[2] = TV[1]; TI[2] = TI[1];                                     \
      TV[1] = (d);   TI[1] = (di);                                      \
    } else if ((d) > TV[2] || ((d) == TV[2] && (di) < TI[2])) {         \
      TV[2] = (d);   TI[2] = (di);                                      \
    }                                                                   \
  }

__global__ __launch_bounds__(512, 4) void k3_topk(const float* __restrict__ tn,
                                                  int* __restrict__ idxo,
                                                  float* __restrict__ attno) {
  __shared__ float smem[C1 * 64 + C1 * 128];   // arow | btile, 55.3 KB
  float* arow  = smem;              // [C1][64]
  float* btile = smem + C1 * 64;    // [C1][128]

  int wg = blockIdx.x;              // 0..511
  int xcd = wg & 7;
  int q = wg >> 3;                  // 0..63
  int b  = xcd * 4 + (q >> 4);      // 4 batches per XCD
  int nt = q & 15;
  int n0 = nt * 64;
  int tid = threadIdx.x;
  int tx = tid & 31;   // col group: cols tx*4..+3 (of 128)
  int ty = tid >> 5;   // row group: rows ty*4..+3 (of 64)

  // stage this block's 64 rows (72 channels)
  for (int e4 = tid; e4 < C1 * 16; e4 += 512) {
    int c = e4 >> 4, qq = e4 & 15;
    *(float4*)&arow[c * 64 + qq * 4] =
        *(const float4*)&tn[(b * C1 + c) * NTOK + n0 + qq * 4];
  }

  float tv[4][3];
  int   ti[4][3];
#pragma unroll
  for (int ri = 0; ri < 4; ++ri) {
    tv[ri][0] = tv[ri][1] = tv[ri][2] = -INFINITY;
    ti[ri][0] = ti[ri][1] = ti[ri][2] = 0x7fffffff;
  }

#pragma unroll 1
  for (int tl = 0; tl < 8; ++tl) {
    int m0 = tl * 128;
    __syncthreads();   // previous tile fully consumed (covers arow staging)
    for (int e4 = tid; e4 < C1 * 32; e4 += 512) {
      int c = e4 >> 5, qq = e4 & 31;
      *(float4*)&btile[c * 128 + qq * 4] =
          *(const float4*)&tn[(b * C1 + c) * NTOK + m0 + qq * 4];
    }
    __syncthreads();

    float4 acc0 = {0,0,0,0}, acc1 = {0,0,0,0}, acc2 = {0,0,0,0}, acc3 = {0,0,0,0};
#pragma unroll 4
    for (int c = 0; c < C1; ++c) {
      float4 av  = *(const float4*)&arow[c * 64 + ty * 4];
      float4 bv4 = *(const float4*)&btile[c * 128 + tx * 4];
      acc0.x += av.x * bv4.x; acc0.y += av.x * bv4.y;
      acc0.z += av.x * bv4.z; acc0.w += av.x * bv4.w;
      acc1.x += av.y * bv4.x; acc1.y += av.y * bv4.y;
      acc1.z += av.y * bv4.z; acc1.w += av.y * bv4.w;
      acc2.x += av.z * bv4.x; acc2.y += av.z * bv4.y;
      acc2.z += av.z * bv4.z; acc2.w += av.z * bv4.w;
      acc3.x += av.w * bv4.x; acc3.y += av.w * bv4.y;
      acc3.z += av.w * bv4.z; acc3.w += av.w * bv4.w;
    }
    int cb = m0 + tx * 4;
    // skip-max: group can only matter if its max beats current 3rd place
    float mx;
    mx = fmaxf(fmaxf(acc0.x, acc0.y), fmaxf(acc0.z, acc0.w));
    if (mx > tv[0][2]) {
      INS(tv[0], ti[0], acc0.x, cb + 0); INS(tv[0], ti[0], acc0.y, cb + 1);
      INS(tv[0], ti[0], acc0.z, cb + 2); INS(tv[0], ti[0], acc0.w, cb + 3);
    }
    mx = fmaxf(fmaxf(acc1.x, acc1.y), fmaxf(acc1.z, acc1.w));
    if (mx > tv[1][2]) {
      INS(tv[1], ti[1], acc1.x, cb + 0); INS(tv[1], ti[1], acc1.y, cb + 1);
      INS(tv[1], ti[1], acc1.z, cb + 2); INS(tv[1], ti[1], acc1.w, cb + 3);
    }
    mx = fmaxf(fmaxf(acc2.x, acc2.y), fmaxf(acc2.z, acc2.w));
    if (mx > tv[2][2]) {
      INS(tv[2], ti[2], acc2.x, cb + 0); INS(tv[2], ti[2], acc2.y, cb + 1);
      INS(tv[2], ti[2], acc2.z, cb + 2); INS(tv[2], ti[2], acc2.w, cb + 3);
    }
    mx = fmaxf(fmaxf(acc3.x, acc3.y), fmaxf(acc3.z, acc3.w));
    if (mx > tv[3][2]) {
      INS(tv[3], ti[3], acc3.x, cb + 0); INS(tv[3], ti[3], acc3.y, cb + 1);
      INS(tv[3], ti[3], acc3.z, cb + 2); INS(tv[3], ti[3], acc3.w, cb + 3);
    }
  }

  // merge 32 col-groups x 3 per row; reuse smem (staging done)
  __syncthreads();
  float* mv = smem;                  // 64*32*3 = 6144 floats
  int*   mi = (int*)(smem + 6144);   // 6144 ints (total 12288 <= 13824)
#pragma unroll
  for (int ri = 0; ri < 4; ++ri) {
    int row = ty * 4 + ri;
#pragma unroll
    for (int j = 0; j < 3; ++j) {
      mv[(row * 32 + tx) * 3 + j] = tv[ri][j];
      mi[(row * 32 + tx) * 3 + j] = ti[ri][j];
    }
  }
  __syncthreads();
  if (tid < 64) {
    float fv[3] = {-INFINITY, -INFINITY, -INFINITY};
    int   fi[3] = {0x7fffffff, 0x7fffffff, 0x7fffffff};
    for (int g = 0; g < 32; ++g) {
#pragma unroll
      for (int j = 0; j < 3; ++j) {
        float d  = mv[(tid * 32 + g) * 3 + j];
        int   di = mi[(tid * 32 + g) * 3 + j];
        INS(fv, fi, d, di);
      }
    }
    float e1 = expf(fv[1] - fv[0]), e2 = expf(fv[2] - fv[0]);
    float inv = 1.0f / (1.0f + e1 + e2);
    int ob = (b * NTOK + n0 + tid) * 3;
    idxo[ob] = fi[0]; idxo[ob + 1] = fi[1]; idxo[ob + 2] = fi[2];
    attno[ob] = inv; attno[ob + 1] = e1 * inv; attno[ob + 2] = e2 * inv;
  }
}

// ---------------------------------------------------------------------------
// Kernel 4: gather top-3 neighbor value columns (x attn) into LDS, then
// conv1d(kernel=K,stride=K) == [72 x 216] GEMM per token.
// NEW: XCD swizzle (4 batches/XCD -> v working set 1.15 MB, L2-resident).
// ---------------------------------------------------------------------------
__global__ __launch_bounds__(256) void k4_conv1d(const float* __restrict__ v,
                                                 const int* __restrict__ idx,
                                                 const float* __restrict__ attn,
                                                 const float* __restrict__ conv_w,
                                                 const float* __restrict__ conv_b,
                                                 float* __restrict__ out1d) {
  __shared__ float prime[64][220];
  __shared__ int   sidx[64][3];
  __shared__ float satt[64][3];
  int wg = blockIdx.x;              // 0..511
  int xcd = wg & 7;
  int q = wg >> 3;                  // 0..63
  int b  = xcd * 4 + (q >> 4);
  int n0 = (q & 15) * 64;
  int tid = threadIdx.x;
  if (tid < 192) {
    int tok = tid / 3, k = tid % 3;
    sidx[tok][k] = idx[(b * NTOK + n0 + tok) * 3 + k];
    satt[tok][k] = attn[(b * NTOK + n0 + tok) * 3 + k];
  }
  __syncthreads();
  for (int e = tid; e < 64 * 216; e += 256) {
    int tok = e & 63, ck = e >> 6;
    int c = ck / 3, k = ck - c * 3;
    prime[tok][ck] = v[(b * C1 + c) * NTOK + sidx[tok][k]] * satt[tok][k];
  }
  __syncthreads();
  int tok = tid & 63;
  int obase = __builtin_amdgcn_readfirstlane((int)(tid >> 6)) * 18;
  float acc[18];
#pragma unroll
  for (int j = 0; j < 18; ++j) acc[j] = 0.f;
  for (int ck4 = 0; ck4 < 54; ++ck4) {
    float4 p4 = *(const float4*)&prime[tok][ck4 * 4];
#pragma unroll
    for (int j = 0; j < 18; ++j) {
      float4 w4 = *(const float4*)&conv_w[(obase + j) * 216 + ck4 * 4];
      acc[j] += p4.x * w4.x + p4.y * w4.y + p4.z * w4.z + p4.w * w4.w;
    }
  }
#pragma unroll
  for (int j = 0; j < 18; ++j) {
    int o = obase + j;
    out1d[(b * C1 + o) * NTOK + n0 + tok] = acc[j] + conv_b[o];
  }
}

// ---------------------------------------------------------------------------
// Kernel 5: pixel_shuffle + pointwise 1x1 conv. (unchanged; streaming, no
// reuse -> XCD swizzle not applicable per T1)
// ---------------------------------------------------------------------------
__global__ __launch_bounds__(256) void k5_pw(const float* __restrict__ out1d,
                                             const float* __restrict__ pw_w,
                                             const float* __restrict__ pw_b,
                                             float* __restrict__ out) {
  int gid = blockIdx.x * 256 + threadIdx.x;   // 131072 threads
  int b = gid >> 12;
  int p = gid & 4095;
  int h = p >> 6, w = p & 63;
  int hh = h >> 1, ww = w >> 1;
  int c1base = ((h & 1) << 1) | (w & 1);
  int n = hh * 32 + ww;
  float xs[18];
#pragma unroll
  for (int c = 0; c < 18; ++c)
    xs[c] = out1d[(b * C1 + c * 4 + c1base) * NTOK + n];
#pragma unroll
  for (int o = 0; o < 16; ++o) {
    float a = pw_b[o];
#pragma unroll
    for (int c = 0; c < 18; ++c) a += xs[c] * pw_w[o * 18 + c];
    out[((b * 16 + o) << 12) + p] = a;
  }
}

// ---------------------------------------------------------------------------
extern "C" void kernel_launch(void* const* d_in, const int* in_sizes, int n_in,
                              void* d_out, int out_size, void* d_ws, size_t ws_size,
                              hipStream_t stream) {
  (void)in_sizes; (void)n_in; (void)out_size; (void)ws_size;
  const float* x      = (const float*)d_in[0];
  const float* Wv     = (const float*)d_in[1];
  const float* bv     = (const float*)d_in[2];
  const float* conv_w = (const float*)d_in[3];
  const float* conv_b = (const float*)d_in[4];
  const float* pw_w   = (const float*)d_in[5];
  const float* pw_b   = (const float*)d_in[6];
  float* out = (float*)d_out;

  const size_t SZ_T = (size_t)BB * C1 * NTOK * sizeof(float);   // 9,437,184
  char* ws = (char*)d_ws;
  float* t     = (float*)(ws);
  float* tn    = (float*)(ws + SZ_T);
  float* v     = (float*)(ws + 2 * SZ_T);
  int*   idx   = (int*)  (ws + 3 * SZ_T);
  float* attn  = (float*)(ws + 3 * SZ_T + 393216);
  float* out1d = (float*)(ws + 3 * SZ_T + 2 * 393216);

  k1_build<<<dim3((BB * NTOK) / 256), 256, 0, stream>>>(x, t, tn);
  k2_vproj<<<dim3(576), 256, 0, stream>>>(t, Wv, bv, v);
  k3_topk <<<dim3(512), 512, 0, stream>>>(tn, idx, attn);
  k4_conv1d<<<dim3(512), 256, 0, stream>>>(v, idx, attn, conv_w, conv_b, out1d);
  k5_pw   <<<dim3((BB * 4096) / 256), 256, 0, stream>>>(out1d, pw_w, pw_b, out);
}